// Round 1
// baseline (706.339 us; speedup 1.0000x reference)
//
#include <hip/hip_runtime.h>

// WindowAttention3D: B=256, N1=384, N2=128, DIM=128, H=4, hd=32, nW=64.
// Round-1 baseline: fused-per-stage pipeline, fp16 operand staging + v_dot2_f32_f16
// inner products (fp32 accumulation). Static __device__ scratch (no ws_size assumption).
//
// Predicted: ~95-120us total; k_attn ~50-60us (HBM-write-bound: 201MB attn probs),
// MfmaUtil=0 (future lever: f16 MFMA), bank conflicts ~0.

typedef _Float16 f16;
typedef _Float16 f16x2 __attribute__((ext_vector_type(2)));
typedef _Float16 f16x4 __attribute__((ext_vector_type(4)));

constexpr int B_  = 256;
constexpr int N1  = 384;
constexpr int N2  = 128;
constexpr int DIM = 128;
constexpr int H_  = 4;
constexpr int HD  = 32;
constexpr float SCALE = 0.17677669529663687f;  // 32^-0.5

// ---- static device scratch (written fully every launch before any read) ----
__device__ f16  g_qp[(long)B_ * N1 * DIM];   // qp*SCALE, layout [b][q][h*32+d]
__device__ f16  g_k [(long)B_ * N2 * DIM];   // [b][n2][h*32+d]
__device__ f16  g_v [(long)B_ * N2 * DIM];   // [b][n2][h*32+d]
__device__ f16  g_x [(long)B_ * N1 * DIM];   // attn@V, [b][q][h*32+d]
__device__ float g_bias[H_ * N1 * N2];       // [h][q][k2]

#if __has_builtin(__builtin_amdgcn_fdot2)
__device__ __forceinline__ float fdot2(f16x2 a, f16x2 b, float c) {
  return __builtin_amdgcn_fdot2(a, b, c, false);
}
#else
__device__ __forceinline__ float fdot2(f16x2 a, f16x2 b, float c) {
  return c + (float)a[0] * (float)b[0] + (float)a[1] * (float)b[1];
}
#endif

// ---------------- K0: bias gather ----------------
__global__ __launch_bounds__(256) void k_bias(const float* __restrict__ tbl,
                                              const int* __restrict__ rel) {
  int g = blockIdx.x * 256 + threadIdx.x;        // < H*N1*N2 = 196608 (grid exact)
  int h = g / (N1 * N2);
  int rem = g - h * (N1 * N2);                   // q*128 + k2
  g_bias[g] = tbl[rel[rem] * H_ + h];
}

// ---- stage fp32 rows -> f16 LDS tile [rows][132] (g pre-offset to first row) ----
__device__ __forceinline__ void stage_f32(const float* __restrict__ g, int ldg,
                                          int rows, f16* lds, int tid) {
  const int chunks = rows * 32;                  // float4 chunks per 128-wide row
  for (int idx = tid; idx < chunks; idx += 256) {
    int r = idx >> 5, c4 = (idx & 31) << 2;
    float4 v = *reinterpret_cast<const float4*>(g + (long)r * ldg + c4);
    f16x2 lo = {(f16)v.x, (f16)v.y};
    f16x2 hi = {(f16)v.z, (f16)v.w};
    f16x2* p = reinterpret_cast<f16x2*>(&lds[r * 132 + c4]);
    p[0] = lo;
    p[1] = hi;
  }
}

// ---- core GEMM: out[64][128] over K=128, As[64][132], Bs[128][132], 256 thr ----
__device__ __forceinline__ void gemm_64x128_k128(const f16* As, const f16* Bs,
                                                 int rg, int cg, float acc[4][8]) {
#pragma unroll 4
  for (int kq = 0; kq < 32; ++kq) {              // 4 halfs (2 dot2-pairs) per iter
    f16x4 a[4], b[8];
#pragma unroll
    for (int i = 0; i < 4; ++i)
      a[i] = *reinterpret_cast<const f16x4*>(&As[(rg + 16 * i) * 132 + 4 * kq]);
#pragma unroll
    for (int j = 0; j < 8; ++j)
      b[j] = *reinterpret_cast<const f16x4*>(&Bs[(cg + 16 * j) * 132 + 4 * kq]);
#pragma unroll
    for (int i = 0; i < 4; ++i) {
#pragma unroll
      for (int j = 0; j < 8; ++j) {
        acc[i][j] = fdot2(__builtin_shufflevector(a[i], a[i], 0, 1),
                          __builtin_shufflevector(b[j], b[j], 0, 1), acc[i][j]);
        acc[i][j] = fdot2(__builtin_shufflevector(a[i], a[i], 2, 3),
                          __builtin_shufflevector(b[j], b[j], 2, 3), acc[i][j]);
      }
    }
  }
}

// ---------------- K1: q projection -> g_qp (pre-scaled) ----------------
__global__ __launch_bounds__(256) void k_qproj(const float* __restrict__ qin,
                                               const float* __restrict__ qw,
                                               const float* __restrict__ qb) {
  __shared__ f16 As[64 * 132];
  __shared__ f16 Bs[128 * 132];
  const int tid = threadIdx.x;
  const long row0 = (long)blockIdx.x * 64;       // rows of (b,q): 98304 total
  stage_f32(qin + row0 * DIM, DIM, 64, As, tid);
  stage_f32(qw, DIM, 128, Bs, tid);
  __syncthreads();
  const int rg = tid & 15, cg = tid >> 4;
  float acc[4][8];
#pragma unroll
  for (int i = 0; i < 4; ++i)
#pragma unroll
    for (int j = 0; j < 8; ++j) acc[i][j] = 0.f;
  gemm_64x128_k128(As, Bs, rg, cg, acc);
#pragma unroll
  for (int i = 0; i < 4; ++i) {
    const long r = row0 + rg + 16 * i;
#pragma unroll
    for (int j = 0; j < 8; ++j) {
      const int c = cg + 16 * j;
      g_qp[r * DIM + c] = (f16)((acc[i][j] + qb[c]) * SCALE);
    }
  }
}

// ---------------- K2: kv projection -> g_k / g_v ----------------
__global__ __launch_bounds__(256) void k_kvproj(const float* __restrict__ kvin,
                                                const float* __restrict__ kvw,
                                                const float* __restrict__ kvb) {
  __shared__ f16 As[64 * 132];
  __shared__ f16 Bs[128 * 132];
  const int tid = threadIdx.x;
  const int rb = blockIdx.x >> 1, ch = blockIdx.x & 1;  // ch: 0=k rows, 1=v rows
  const long row0 = (long)rb * 64;               // rows of (b,n2): 32768 total
  stage_f32(kvin + row0 * DIM, DIM, 64, As, tid);
  stage_f32(kvw + (long)ch * 128 * DIM, DIM, 128, Bs, tid);
  __syncthreads();
  const int rg = tid & 15, cg = tid >> 4;
  float acc[4][8];
#pragma unroll
  for (int i = 0; i < 4; ++i)
#pragma unroll
    for (int j = 0; j < 8; ++j) acc[i][j] = 0.f;
  gemm_64x128_k128(As, Bs, rg, cg, acc);
  f16* dst = ch ? g_v : g_k;
#pragma unroll
  for (int i = 0; i < 4; ++i) {
    const long r = row0 + rg + 16 * i;
#pragma unroll
    for (int j = 0; j < 8; ++j) {
      const int c = cg + 16 * j;                 // c = h*32+d
      dst[r * DIM + c] = (f16)(acc[i][j] + kvb[ch * 128 + c]);
    }
  }
}

// ---------------- K3: attention per (b,h) ----------------
__global__ __launch_bounds__(256) void k_attn(const float* __restrict__ mask,
                                              float* __restrict__ outAttn) {
  __shared__ f16 kS[128 * 36];      // k_h [n2][d], stride 36 halfs
  __shared__ f16 vT[32 * 132];      // v_h^T [d][n2], stride 132 halfs
  __shared__ f16 qpT[64 * 36];      // qp tile [q][d]
  __shared__ float pF[64 * 136];    // logits fp32
  __shared__ f16 pH[64 * 132];      // probs f16 (PV A-operand)
  const int tid = threadIdx.x;
  const int b = blockIdx.x >> 2, h = blockIdx.x & 3, w = b & 63;

  // stage k_h (uint2 = 4 halfs)
  for (int idx = tid; idx < 128 * 8; idx += 256) {
    int n2 = idx >> 3, dq = idx & 7;
    uint2 v = *reinterpret_cast<const uint2*>(
        &g_k[((long)(b * N2 + n2)) * DIM + h * HD + dq * 4]);
    *reinterpret_cast<uint2*>(&kS[n2 * 36 + dq * 4]) = v;
  }
  // stage v_h transposed
  for (int idx = tid; idx < 128 * 8; idx += 256) {
    int n2 = idx >> 3, dq = idx & 7;
    uint2 v = *reinterpret_cast<const uint2*>(
        &g_v[((long)(b * N2 + n2)) * DIM + h * HD + dq * 4]);
    f16 tmp[4];
    *reinterpret_cast<uint2*>(tmp) = v;
#pragma unroll
    for (int t = 0; t < 4; ++t) vT[(dq * 4 + t) * 132 + n2] = tmp[t];
  }

  for (int t6 = 0; t6 < 6; ++t6) {
    const int q0 = t6 * 64;
    __syncthreads();  // staging done (t6=0) / previous tile fully consumed
    for (int idx = tid; idx < 64 * 8; idx += 256) {
      int r = idx >> 3, dq = idx & 7;
      uint2 v = *reinterpret_cast<const uint2*>(
          &g_qp[((long)(b * N1 + q0 + r)) * DIM + h * HD + dq * 4]);
      *reinterpret_cast<uint2*>(&qpT[r * 36 + dq * 4]) = v;
    }
    __syncthreads();

    // QK^T: out[64 q][128 n2], K=32
    const int rg = tid & 15, cg = tid >> 4;
    float acc[4][8];
#pragma unroll
    for (int i = 0; i < 4; ++i)
#pragma unroll
      for (int j = 0; j < 8; ++j) acc[i][j] = 0.f;
#pragma unroll
    for (int kq = 0; kq < 8; ++kq) {
      f16x4 a[4], bb[8];
#pragma unroll
      for (int i = 0; i < 4; ++i)
        a[i] = *reinterpret_cast<const f16x4*>(&qpT[(rg + 16 * i) * 36 + 4 * kq]);
#pragma unroll
      for (int j = 0; j < 8; ++j)
        bb[j] = *reinterpret_cast<const f16x4*>(&kS[(cg + 16 * j) * 36 + 4 * kq]);
#pragma unroll
      for (int i = 0; i < 4; ++i)
#pragma unroll
        for (int j = 0; j < 8; ++j) {
          acc[i][j] = fdot2(__builtin_shufflevector(a[i], a[i], 0, 1),
                            __builtin_shufflevector(bb[j], bb[j], 0, 1), acc[i][j]);
          acc[i][j] = fdot2(__builtin_shufflevector(a[i], a[i], 2, 3),
                            __builtin_shufflevector(bb[j], bb[j], 2, 3), acc[i][j]);
        }
    }
#pragma unroll
    for (int i = 0; i < 4; ++i)
#pragma unroll
      for (int j = 0; j < 8; ++j) pF[(rg + 16 * i) * 136 + cg + 16 * j] = acc[i][j];
    __syncthreads();

    // softmax: wave per 16 rows; lane covers n2 = {2l, 2l+1}; bias+mask fused here
    const int wid = tid >> 6, lane = tid & 63;
    for (int rr = 0; rr < 16; ++rr) {
      const int r = wid * 16 + rr;
      const int qq = q0 + r;
      float x0 = pF[r * 136 + 2 * lane];
      float x1 = pF[r * 136 + 2 * lane + 1];
      float2 bi = *reinterpret_cast<const float2*>(&g_bias[(h * N1 + qq) * N2 + 2 * lane]);
      float2 mk = *reinterpret_cast<const float2*>(&mask[((long)w * N1 + qq) * N2 + 2 * lane]);
      x0 += bi.x + mk.x;
      x1 += bi.y + mk.y;
      float m = fmaxf(x0, x1);
#pragma unroll
      for (int off = 32; off; off >>= 1) m = fmaxf(m, __shfl_xor(m, off));
      float e0 = __expf(x0 - m), e1 = __expf(x1 - m);
      float s = e0 + e1;
#pragma unroll
      for (int off = 32; off; off >>= 1) s += __shfl_xor(s, off);
      float inv = 1.0f / s;
      float p0 = e0 * inv, p1 = e1 * inv;
      *reinterpret_cast<float2*>(
          &outAttn[(((long)(b * H_ + h) * N1) + qq) * N2 + 2 * lane]) = float2{p0, p1};
      reinterpret_cast<f16x2*>(&pH[r * 132])[lane] = f16x2{(f16)p0, (f16)p1};
    }
    __syncthreads();

    // PV: out[64 q][32 d], K=128 (n2)
    const int rg2 = tid & 31, cg2 = tid >> 5;
    float acc2[2][4];
#pragma unroll
    for (int i = 0; i < 2; ++i)
#pragma unroll
      for (int j = 0; j < 4; ++j) acc2[i][j] = 0.f;
    const f16x2* pH2 = reinterpret_cast<const f16x2*>(pH);   // row stride 66
    const f16x2* vT2 = reinterpret_cast<const f16x2*>(vT);   // row stride 66
#pragma unroll 4
    for (int n22 = 0; n22 < 64; ++n22) {
      f16x2 a0 = pH2[rg2 * 66 + n22];
      f16x2 a1 = pH2[(rg2 + 32) * 66 + n22];
      f16x2 bb[4];
#pragma unroll
      for (int j = 0; j < 4; ++j) bb[j] = vT2[(cg2 + 8 * j) * 66 + n22];
#pragma unroll
      for (int j = 0; j < 4; ++j) {
        acc2[0][j] = fdot2(a0, bb[j], acc2[0][j]);
        acc2[1][j] = fdot2(a1, bb[j], acc2[1][j]);
      }
    }
#pragma unroll
    for (int i = 0; i < 2; ++i) {
      const int qq = q0 + rg2 + 32 * i;
#pragma unroll
      for (int j = 0; j < 4; ++j) {
        const int d = cg2 + 8 * j;
        g_x[((long)(b * N1) + qq) * DIM + h * HD + d] = (f16)acc2[i][j];
      }
    }
  }
}

// ---------------- K4: output projection + bias + residual ----------------
__global__ __launch_bounds__(256) void k_proj(const float* __restrict__ qin,
                                              const float* __restrict__ pw,
                                              const float* __restrict__ pb,
                                              float* __restrict__ outX) {
  __shared__ f16 As[64 * 132];
  __shared__ f16 Bs[128 * 132];
  const int tid = threadIdx.x;
  const long row0 = (long)blockIdx.x * 64;
  for (int idx = tid; idx < 64 * 32; idx += 256) {  // g_x already f16: plain copy
    int r = idx >> 5, c4 = (idx & 31) << 2;
    uint2 v = *reinterpret_cast<const uint2*>(&g_x[(row0 + r) * DIM + c4]);
    *reinterpret_cast<uint2*>(&As[r * 132 + c4]) = v;
  }
  stage_f32(pw, DIM, 128, Bs, tid);
  __syncthreads();
  const int rg = tid & 15, cg = tid >> 4;
  float acc[4][8];
#pragma unroll
  for (int i = 0; i < 4; ++i)
#pragma unroll
    for (int j = 0; j < 8; ++j) acc[i][j] = 0.f;
  gemm_64x128_k128(As, Bs, rg, cg, acc);
#pragma unroll
  for (int i = 0; i < 4; ++i) {
    const long r = row0 + rg + 16 * i;
#pragma unroll
    for (int j = 0; j < 8; ++j) {
      const int c = cg + 16 * j;
      outX[r * DIM + c] = acc[i][j] + pb[c] + qin[r * DIM + c];
    }
  }
}

extern "C" void kernel_launch(void* const* d_in, const int* in_sizes, int n_in,
                              void* d_out, int out_size, void* d_ws, size_t ws_size,
                              hipStream_t stream) {
  (void)in_sizes; (void)n_in; (void)out_size; (void)d_ws; (void)ws_size;
  const float* q    = (const float*)d_in[0];
  const float* kv   = (const float*)d_in[1];
  const float* mask = (const float*)d_in[2];
  const float* qw   = (const float*)d_in[3];
  const float* qb   = (const float*)d_in[4];
  const float* kvw  = (const float*)d_in[5];
  const float* kvb  = (const float*)d_in[6];
  const float* pw   = (const float*)d_in[7];
  const float* pb   = (const float*)d_in[8];
  const float* tbl  = (const float*)d_in[9];
  const int*   rel  = (const int*)d_in[10];

  float* outX = (float*)d_out;                       // (B, N1, DIM)
  float* outA = outX + (long)B_ * N1 * DIM;          // (B, H, N1, N2)

  hipLaunchKernelGGL(k_bias,   dim3(768),  dim3(256), 0, stream, tbl, rel);
  hipLaunchKernelGGL(k_qproj,  dim3(1536), dim3(256), 0, stream, q, qw, qb);
  hipLaunchKernelGGL(k_kvproj, dim3(1024), dim3(256), 0, stream, kv, kvw, kvb);
  hipLaunchKernelGGL(k_attn,   dim3(1024), dim3(256), 0, stream, mask, outA);
  hipLaunchKernelGGL(k_proj,   dim3(1536), dim3(256), 0, stream, q, pw, pb, outX);
}

// Round 4
// 483.942 us; speedup vs baseline: 1.4596x; 1.4596x over previous
//
#include <hip/hip_runtime.h>

// WindowAttention3D: B=256, N1=384, N2=128, DIM=128, H=4, hd=32, nW=64.
// Round-4 (= round-2 design, compile fix: no braced-init inside macro arg):
// full MFMA rewrite (v_mfma_f32_16x16x32_f16), barrier-free attn main loop,
// fragments direct-from-global (L1/L2-hot), f16 weights preconverted.

typedef _Float16 f16;
typedef _Float16 f16x4 __attribute__((ext_vector_type(4)));
typedef _Float16 f16x8 __attribute__((ext_vector_type(8)));
typedef float    f32x4 __attribute__((ext_vector_type(4)));

#define MFMA16(a, b, c) __builtin_amdgcn_mfma_f32_16x16x32_f16((a), (b), (c), 0, 0, 0)

constexpr int B_  = 256;
constexpr int N1  = 384;
constexpr int N2  = 128;
constexpr int DIM = 128;
constexpr int H_  = 4;
constexpr int HD  = 32;
constexpr float SCALE = 0.17677669529663687f;  // 32^-0.5

// ---- static device scratch (fully written every launch before any read) ----
__device__ alignas(16) f16  g_qp[(long)B_ * N1 * DIM];   // qp*SCALE  [b][q][h*32+d]
__device__ alignas(16) f16  g_k [(long)B_ * N2 * DIM];   // [b][n2][h*32+d]
__device__ alignas(16) f16  g_v [(long)B_ * N2 * DIM];   // [b][n2][h*32+d]
__device__ alignas(16) f16  g_x [(long)B_ * N1 * DIM];   // attn@V   [b][q][h*32+d]
__device__ float g_bias[H_ * N1 * N2];                   // [h][q][n2]
__device__ alignas(16) f16  g_wq [DIM * DIM];            // [out][in] f16
__device__ alignas(16) f16  g_wkv[2 * DIM * DIM];
__device__ alignas(16) f16  g_wp [DIM * DIM];

// ---------------- P0: weight f32->f16 convert ----------------
__global__ __launch_bounds__(256) void k_wcvt(const float* __restrict__ qw,
                                              const float* __restrict__ kvw,
                                              const float* __restrict__ pw) {
  int i4 = (blockIdx.x * 256 + threadIdx.x) * 4;   // 65536 floats total, grid 64
  const float* src;
  f16* dst;
  int off;
  if (i4 < 16384)      { src = qw;  dst = g_wq;  off = i4; }
  else if (i4 < 49152) { src = kvw; dst = g_wkv; off = i4 - 16384; }
  else                 { src = pw;  dst = g_wp;  off = i4 - 49152; }
  float4 v = *reinterpret_cast<const float4*>(src + off);
  f16x4 h = {(f16)v.x, (f16)v.y, (f16)v.z, (f16)v.w};
  *reinterpret_cast<f16x4*>(dst + off) = h;
}

// ---------------- P1: bias gather ----------------
__global__ __launch_bounds__(256) void k_bias(const float* __restrict__ tbl,
                                              const int* __restrict__ rel) {
  int g = blockIdx.x * 256 + threadIdx.x;          // H*N1*N2 = 196608, grid 768
  int h = g / (N1 * N2);
  int rem = g - h * (N1 * N2);
  g_bias[g] = tbl[rel[rem] * H_ + h];
}

// ======== MFMA GEMM: C[64 x 128] = A[64 x 128] * W^T, W=[128 out][128 in] ======
// wave wv owns rows wv*16..wv*16+16; lane: lr=l&15 (row/col-in-tile), lg=l>>4.
// A-frag: A[lr][lg*8+:8]; W-frag: W[col=lr][lg*8+:8]; D: col=lr, row=lg*4+reg.

// ---------------- K1: q projection ----------------
__global__ __launch_bounds__(256, 4) void k_qproj(const float* __restrict__ qin,
                                                  const float* __restrict__ qb) {
  __shared__ alignas(16) f16 As[64 * 136];
  const int tid = threadIdx.x, wv = tid >> 6, l = tid & 63, lr = l & 15, lg = l >> 4;
  const long row0 = (long)blockIdx.x * 64;         // 98304 rows, grid 1536
  for (int idx = tid; idx < 2048; idx += 256) {    // 64x128 f32 -> f16 LDS
    int r = idx >> 5, c4 = (idx & 31) << 2;
    float4 v = *reinterpret_cast<const float4*>(qin + (row0 + r) * DIM + c4);
    f16x4 h = {(f16)v.x, (f16)v.y, (f16)v.z, (f16)v.w};
    *reinterpret_cast<f16x4*>(&As[r * 136 + c4]) = h;
  }
  __syncthreads();
  f32x4 acc[8] = {};
#pragma unroll
  for (int ks = 0; ks < 4; ++ks) {
    f16x8 a = *reinterpret_cast<const f16x8*>(&As[(wv * 16 + lr) * 136 + ks * 32 + lg * 8]);
#pragma unroll
    for (int j = 0; j < 8; ++j) {
      f16x8 w = *reinterpret_cast<const f16x8*>(&g_wq[(j * 16 + lr) * DIM + ks * 32 + lg * 8]);
      acc[j] = MFMA16(a, w, acc[j]);
    }
  }
  const long rbase = row0 + wv * 16 + lg * 4;
#pragma unroll
  for (int j = 0; j < 8; ++j) {
    int c = j * 16 + lr;
    float bv = qb[c];
#pragma unroll
    for (int r = 0; r < 4; ++r)
      g_qp[(rbase + r) * DIM + c] = (f16)((acc[j][r] + bv) * SCALE);
  }
}

// ---------------- K2: kv projection ----------------
__global__ __launch_bounds__(256, 4) void k_kvproj(const float* __restrict__ kvin,
                                                   const float* __restrict__ kvb) {
  __shared__ alignas(16) f16 As[64 * 136];
  const int tid = threadIdx.x, wv = tid >> 6, l = tid & 63, lr = l & 15, lg = l >> 4;
  const int rb = blockIdx.x & 511, ch = blockIdx.x >> 9;   // grid 1024
  const long row0 = (long)rb * 64;                 // 32768 rows of (b,n2)
  for (int idx = tid; idx < 2048; idx += 256) {
    int r = idx >> 5, c4 = (idx & 31) << 2;
    float4 v = *reinterpret_cast<const float4*>(kvin + (row0 + r) * DIM + c4);
    f16x4 h = {(f16)v.x, (f16)v.y, (f16)v.z, (f16)v.w};
    *reinterpret_cast<f16x4*>(&As[r * 136 + c4]) = h;
  }
  __syncthreads();
  const f16* W = g_wkv + (long)ch * DIM * DIM;
  f32x4 acc[8] = {};
#pragma unroll
  for (int ks = 0; ks < 4; ++ks) {
    f16x8 a = *reinterpret_cast<const f16x8*>(&As[(wv * 16 + lr) * 136 + ks * 32 + lg * 8]);
#pragma unroll
    for (int j = 0; j < 8; ++j) {
      f16x8 w = *reinterpret_cast<const f16x8*>(&W[(j * 16 + lr) * DIM + ks * 32 + lg * 8]);
      acc[j] = MFMA16(a, w, acc[j]);
    }
  }
  f16* dst = ch ? g_v : g_k;
  const long rbase = row0 + wv * 16 + lg * 4;
#pragma unroll
  for (int j = 0; j < 8; ++j) {
    int c = j * 16 + lr;
    float bv = kvb[ch * DIM + c];
#pragma unroll
    for (int r = 0; r < 4; ++r)
      dst[(rbase + r) * DIM + c] = (f16)(acc[j][r] + bv);
  }
}

// ---------------- K3: attention per (b,h) — barrier-free main loop ----------
__global__ __launch_bounds__(256, 4) void k_attn(const float* __restrict__ mask,
                                                 float* __restrict__ outAttn) {
  __shared__ alignas(16) f16 vT[32 * 136];   // v_h^T [d][n2]
  __shared__ alignas(16) f16 pS[64 * 136];   // probs f16, wave-private 16-row bands
  const int tid = threadIdx.x, wv = tid >> 6, l = tid & 63, lr = l & 15, lg = l >> 4;
  const int h = blockIdx.x >> 8, b = blockIdx.x & 255, wm = b & 63;

  const f16* gk = g_k + (long)b * N2 * DIM + h * HD;
  const f16* gv = g_v + (long)b * N2 * DIM + h * HD;
  const f16* gq = g_qp + (long)b * N1 * DIM + h * HD;
  float* oA = outAttn + ((long)(b * H_ + h)) * N1 * N2;
  const float* mk = mask + (long)wm * N1 * N2;
  const float* bi = g_bias + (long)h * N1 * N2;

  // stage v transposed (only LDS staging needed)
  for (int idx = tid; idx < 512; idx += 256) {
    int n2 = idx >> 2, c8 = (idx & 3) * 8;
    f16x8 v = *reinterpret_cast<const f16x8*>(gv + n2 * DIM + c8);
#pragma unroll
    for (int t = 0; t < 8; ++t) vT[(c8 + t) * 136 + n2] = v[t];
  }
  __syncthreads();

  for (int t6 = 0; t6 < 6; ++t6) {
    const int q0 = t6 * 64;
    // QK^T: A-frag direct from global (16B), K-frags direct from global (L1-hot)
    f16x8 afr = *reinterpret_cast<const f16x8*>(gq + (q0 + wv * 16 + lr) * DIM + lg * 8);
    const f32x4 fz = {};
    f32x4 s[8];
#pragma unroll
    for (int j = 0; j < 8; ++j) {
      f16x8 kf = *reinterpret_cast<const f16x8*>(gk + (j * 16 + lr) * DIM + lg * 8);
      s[j] = MFMA16(afr, kf, fz);
    }
    // bias + mask + row softmax (rows live in regs; reduce over 16 lr-lanes)
    const int qrb = q0 + wv * 16 + lg * 4;
#pragma unroll
    for (int r = 0; r < 4; ++r) {
      const long off = (long)(qrb + r) * N2 + lr;
#pragma unroll
      for (int j = 0; j < 8; ++j) s[j][r] += bi[off + 16 * j] + mk[off + 16 * j];
      float m = s[0][r];
#pragma unroll
      for (int j = 1; j < 8; ++j) m = fmaxf(m, s[j][r]);
#pragma unroll
      for (int o = 8; o; o >>= 1) m = fmaxf(m, __shfl_xor(m, o));
      float sum = 0.f;
#pragma unroll
      for (int j = 0; j < 8; ++j) { s[j][r] = __expf(s[j][r] - m); sum += s[j][r]; }
#pragma unroll
      for (int o = 8; o; o >>= 1) sum += __shfl_xor(sum, o);
      const float inv = 1.0f / sum;
#pragma unroll
      for (int j = 0; j < 8; ++j) {
        float p = s[j][r] * inv;
        oA[off + 16 * j] = p;
        pS[(wv * 16 + lg * 4 + r) * 136 + 16 * j + lr] = (f16)p;
      }
    }
    // PV: X[16q x 32d] = P[16 x 128] * v[128 x 32]; pS band is wave-private,
    // in-wave ds_write->ds_read ordering (DS pipe in-order per wave, no barrier).
    f32x4 x0 = {}, x1 = {};
#pragma unroll
    for (int ks = 0; ks < 4; ++ks) {
      f16x8 pa = *reinterpret_cast<const f16x8*>(&pS[(wv * 16 + lr) * 136 + ks * 32 + lg * 8]);
      f16x8 b0 = *reinterpret_cast<const f16x8*>(&vT[lr * 136 + ks * 32 + lg * 8]);
      f16x8 b1 = *reinterpret_cast<const f16x8*>(&vT[(16 + lr) * 136 + ks * 32 + lg * 8]);
      x0 = MFMA16(pa, b0, x0);
      x1 = MFMA16(pa, b1, x1);
    }
    f16* gx = g_x + ((long)b * N1 + q0 + wv * 16 + lg * 4) * DIM + h * HD;
#pragma unroll
    for (int r = 0; r < 4; ++r) {
      gx[r * DIM + lr] = (f16)x0[r];
      gx[r * DIM + 16 + lr] = (f16)x1[r];
    }
  }
}

// ---------------- K4: out projection + bias + residual ----------------
__global__ __launch_bounds__(256, 4) void k_proj(const float* __restrict__ qin,
                                                 const float* __restrict__ pb,
                                                 float* __restrict__ outX) {
  __shared__ alignas(16) f16 As[64 * 136];
  const int tid = threadIdx.x, wv = tid >> 6, l = tid & 63, lr = l & 15, lg = l >> 4;
  const long row0 = (long)blockIdx.x * 64;         // grid 1536
  for (int idx = tid; idx < 1024; idx += 256) {    // g_x already f16: copy
    int r = idx >> 4, c8 = (idx & 15) * 8;
    *reinterpret_cast<f16x8*>(&As[r * 136 + c8]) =
        *reinterpret_cast<const f16x8*>(g_x + (row0 + r) * DIM + c8);
  }
  __syncthreads();
  f32x4 acc[8] = {};
#pragma unroll
  for (int ks = 0; ks < 4; ++ks) {
    f16x8 a = *reinterpret_cast<const f16x8*>(&As[(wv * 16 + lr) * 136 + ks * 32 + lg * 8]);
#pragma unroll
    for (int j = 0; j < 8; ++j) {
      f16x8 w = *reinterpret_cast<const f16x8*>(&g_wp[(j * 16 + lr) * DIM + ks * 32 + lg * 8]);
      acc[j] = MFMA16(a, w, acc[j]);
    }
  }
  const long rbase = row0 + wv * 16 + lg * 4;
#pragma unroll
  for (int j = 0; j < 8; ++j) {
    int c = j * 16 + lr;
    float bv = pb[c];
#pragma unroll
    for (int r = 0; r < 4; ++r) {
      long idx = (rbase + r) * DIM + c;
      outX[idx] = acc[j][r] + bv + qin[idx];
    }
  }
}

extern "C" void kernel_launch(void* const* d_in, const int* in_sizes, int n_in,
                              void* d_out, int out_size, void* d_ws, size_t ws_size,
                              hipStream_t stream) {
  (void)in_sizes; (void)n_in; (void)out_size; (void)d_ws; (void)ws_size;
  const float* q    = (const float*)d_in[0];
  const float* kv   = (const float*)d_in[1];
  const float* mask = (const float*)d_in[2];
  const float* qw   = (const float*)d_in[3];
  const float* qb   = (const float*)d_in[4];
  const float* kvw  = (const float*)d_in[5];
  const float* kvb  = (const float*)d_in[6];
  const float* pw   = (const float*)d_in[7];
  const float* pb   = (const float*)d_in[8];
  const float* tbl  = (const float*)d_in[9];
  const int*   rel  = (const int*)d_in[10];

  float* outX = (float*)d_out;                     // (B, N1, DIM)
  float* outA = outX + (long)B_ * N1 * DIM;        // (B, H, N1, N2)

  hipLaunchKernelGGL(k_wcvt,   dim3(64),   dim3(256), 0, stream, qw, kvw, pw);
  hipLaunchKernelGGL(k_bias,   dim3(768),  dim3(256), 0, stream, tbl, rel);
  hipLaunchKernelGGL(k_qproj,  dim3(1536), dim3(256), 0, stream, q, qb);
  hipLaunchKernelGGL(k_kvproj, dim3(1024), dim3(256), 0, stream, kv, kvb);
  hipLaunchKernelGGL(k_attn,   dim3(1024), dim3(256), 0, stream, mask, outA);
  hipLaunchKernelGGL(k_proj,   dim3(1536), dim3(256), 0, stream, q, pb, outX);
}

// Round 5
// 452.902 us; speedup vs baseline: 1.5596x; 1.0685x over previous
//
#include <hip/hip_runtime.h>

// WindowAttention3D: B=256, N1=384, N2=128, DIM=128, H=4, hd=32, nW=64.
// Round-5: fuse out-proj into attn (block = (b, q-tile) x 4 heads, x stays in
// wave-private LDS band); bias+mask precombined to one f16 table; XCD swizzle;
// 4 launches total. All matmuls v_mfma_f32_16x16x32_f16.

typedef _Float16 f16;
typedef _Float16 f16x2 __attribute__((ext_vector_type(2)));
typedef _Float16 f16x4 __attribute__((ext_vector_type(4)));
typedef _Float16 f16x8 __attribute__((ext_vector_type(8)));
typedef float    f32x4 __attribute__((ext_vector_type(4)));

#define MFMA16(a, b, c) __builtin_amdgcn_mfma_f32_16x16x32_f16((a), (b), (c), 0, 0, 0)

constexpr int B_  = 256;
constexpr int N1  = 384;
constexpr int N2  = 128;
constexpr int DIM = 128;
constexpr int H_  = 4;
constexpr int HD  = 32;
constexpr int NW  = 64;
constexpr float SCALE = 0.17677669529663687f;  // 32^-0.5

// ---- static device scratch (fully written every launch before any read) ----
__device__ alignas(16) f16 g_qp[(long)B_ * N1 * DIM];    // qp*SCALE [b][q][h*32+d]
__device__ alignas(16) f16 g_k [(long)B_ * N2 * DIM];    // [b][n2][h*32+d]
__device__ alignas(16) f16 g_v [(long)B_ * N2 * DIM];    // [b][n2][h*32+d]
__device__ alignas(4)  f16 g_bm[(long)H_ * NW * N1 * N2];// bias+mask f16 [h][wm][q][k]
__device__ alignas(16) f16 g_wq [DIM * DIM];             // [out][in] f16
__device__ alignas(16) f16 g_wkv[2 * DIM * DIM];
__device__ alignas(16) f16 g_wp [DIM * DIM];

// ---------------- P0: prep = weight cvt + (bias gather + mask) f16 table ------
// blocks [0, 24576): g_bm pairs; blocks [24576, 24640): weight convert.
__global__ __launch_bounds__(256) void k_prep(const float* __restrict__ mask,
                                              const float* __restrict__ tbl,
                                              const int* __restrict__ rel,
                                              const float* __restrict__ qw,
                                              const float* __restrict__ kvw,
                                              const float* __restrict__ pw) {
  if (blockIdx.x < 24576) {
    long p2 = ((long)blockIdx.x * 256 + threadIdx.x) * 2;   // even element index
    int h = (int)(p2 / (NW * N1 * N2));
    long rem = p2 - (long)h * (NW * N1 * N2);
    int wm = (int)(rem / (N1 * N2));
    long qk = rem - (long)wm * (N1 * N2);                   // q*128 + k (k even)
    float2 mk = *reinterpret_cast<const float2*>(mask + (long)wm * N1 * N2 + qk);
    int r0 = rel[qk], r1 = rel[qk + 1];
    f16x2 o = {(f16)(tbl[r0 * H_ + h] + mk.x), (f16)(tbl[r1 * H_ + h] + mk.y)};
    *reinterpret_cast<f16x2*>(g_bm + p2) = o;
  } else {
    int i4 = ((blockIdx.x - 24576) * 256 + threadIdx.x) * 4;  // 65536 floats
    const float* src;
    f16* dst;
    int off;
    if (i4 < 16384)      { src = qw;  dst = g_wq;  off = i4; }
    else if (i4 < 49152) { src = kvw; dst = g_wkv; off = i4 - 16384; }
    else                 { src = pw;  dst = g_wp;  off = i4 - 49152; }
    float4 v = *reinterpret_cast<const float4*>(src + off);
    f16x4 h4 = {(f16)v.x, (f16)v.y, (f16)v.z, (f16)v.w};
    *reinterpret_cast<f16x4*>(dst + off) = h4;
  }
}

// ======== MFMA GEMM frag map (16x16x32 f16) ========
// lane l: lr=l&15, lg=l>>4. A-frag: A[row=lr][k=lg*8..+8]; B-frag: B^T[col=lr][k=lg*8..+8];
// D: col=lr, row=lg*4+reg.

// ---------------- K1: q projection ----------------
__global__ __launch_bounds__(256, 4) void k_qproj(const float* __restrict__ qin,
                                                  const float* __restrict__ qb) {
  __shared__ alignas(16) f16 As[64 * 136];
  const int tid = threadIdx.x, wv = tid >> 6, l = tid & 63, lr = l & 15, lg = l >> 4;
  const long row0 = (long)blockIdx.x * 64;         // 98304 rows, grid 1536
  for (int idx = tid; idx < 2048; idx += 256) {
    int r = idx >> 5, c4 = (idx & 31) << 2;
    float4 v = *reinterpret_cast<const float4*>(qin + (row0 + r) * DIM + c4);
    f16x4 h = {(f16)v.x, (f16)v.y, (f16)v.z, (f16)v.w};
    *reinterpret_cast<f16x4*>(&As[r * 136 + c4]) = h;
  }
  __syncthreads();
  f32x4 acc[8] = {};
#pragma unroll
  for (int ks = 0; ks < 4; ++ks) {
    f16x8 a = *reinterpret_cast<const f16x8*>(&As[(wv * 16 + lr) * 136 + ks * 32 + lg * 8]);
#pragma unroll
    for (int j = 0; j < 8; ++j) {
      f16x8 w = *reinterpret_cast<const f16x8*>(&g_wq[(j * 16 + lr) * DIM + ks * 32 + lg * 8]);
      acc[j] = MFMA16(a, w, acc[j]);
    }
  }
  const long rbase = row0 + wv * 16 + lg * 4;
#pragma unroll
  for (int j = 0; j < 8; ++j) {
    int c = j * 16 + lr;
    float bv = qb[c];
#pragma unroll
    for (int r = 0; r < 4; ++r)
      g_qp[(rbase + r) * DIM + c] = (f16)((acc[j][r] + bv) * SCALE);
  }
}

// ---------------- K2: kv projection ----------------
__global__ __launch_bounds__(256, 4) void k_kvproj(const float* __restrict__ kvin,
                                                   const float* __restrict__ kvb) {
  __shared__ alignas(16) f16 As[64 * 136];
  const int tid = threadIdx.x, wv = tid >> 6, l = tid & 63, lr = l & 15, lg = l >> 4;
  const int rb = blockIdx.x & 511, ch = blockIdx.x >> 9;   // grid 1024
  const long row0 = (long)rb * 64;                 // 32768 rows of (b,n2)
  for (int idx = tid; idx < 2048; idx += 256) {
    int r = idx >> 5, c4 = (idx & 31) << 2;
    float4 v = *reinterpret_cast<const float4*>(kvin + (row0 + r) * DIM + c4);
    f16x4 h = {(f16)v.x, (f16)v.y, (f16)v.z, (f16)v.w};
    *reinterpret_cast<f16x4*>(&As[r * 136 + c4]) = h;
  }
  __syncthreads();
  const f16* W = g_wkv + (long)ch * DIM * DIM;
  f32x4 acc[8] = {};
#pragma unroll
  for (int ks = 0; ks < 4; ++ks) {
    f16x8 a = *reinterpret_cast<const f16x8*>(&As[(wv * 16 + lr) * 136 + ks * 32 + lg * 8]);
#pragma unroll
    for (int j = 0; j < 8; ++j) {
      f16x8 w = *reinterpret_cast<const f16x8*>(&W[(j * 16 + lr) * DIM + ks * 32 + lg * 8]);
      acc[j] = MFMA16(a, w, acc[j]);
    }
  }
  f16* dst = ch ? g_v : g_k;
  const long rbase = row0 + wv * 16 + lg * 4;
#pragma unroll
  for (int j = 0; j < 8; ++j) {
    int c = j * 16 + lr;
    float bv = kvb[ch * DIM + c];
#pragma unroll
    for (int r = 0; r < 4; ++r)
      dst[(rbase + r) * DIM + c] = (f16)(acc[j][r] + bv);
  }
}

// ---------------- K3: fused attention + out-proj; block = (b, q-tile) --------
__global__ __launch_bounds__(256, 3) void k_fused(const float* __restrict__ qin,
                                                  const float* __restrict__ pb,
                                                  float* __restrict__ outX,
                                                  float* __restrict__ outAttn) {
  __shared__ alignas(16) f16 vT[32 * 136];   // v_h^T [d][n2], restaged per head
  __shared__ alignas(16) f16 pS[64 * 136];   // probs f16, wave-private bands
  __shared__ alignas(16) f16 xS[64 * 136];   // attn@V f16, wave-private bands
  const int tid = threadIdx.x, wv = tid >> 6, l = tid & 63, lr = l & 15, lg = l >> 4;
  // XCD swizzle: grid 1536 = 8 XCDs x 192; same-b tiles stay on one XCD.
  const int xcd = blockIdx.x & 7, j5 = blockIdx.x >> 3;
  const int b = xcd + 8 * (j5 / 6), t6 = j5 % 6;
  const int wm = b & 63, q0 = t6 * 64;

  const f16* gq = g_qp + ((long)b * N1 + q0) * DIM;
  const f16* gk = g_k + (long)b * N2 * DIM;
  const f16* gv = g_v + (long)b * N2 * DIM;
  float* oA = outAttn + (long)b * H_ * N1 * N2;
  const f32x4 fz = {};

#pragma unroll 1
  for (int h = 0; h < H_; ++h) {
    __syncthreads();  // vT free (prev head's PV complete); no-op cost at h=0
    for (int idx = tid; idx < 512; idx += 256) {   // stage v_h^T
      int n2 = idx >> 2, c8 = (idx & 3) * 8;
      f16x8 v = *reinterpret_cast<const f16x8*>(gv + n2 * DIM + h * HD + c8);
#pragma unroll
      for (int t = 0; t < 8; ++t) vT[(c8 + t) * 136 + n2] = v[t];
    }
    __syncthreads();  // vT ready

    // QK^T: fragments direct from global (L1/L2-hot)
    f16x8 afr = *reinterpret_cast<const f16x8*>(gq + (wv * 16 + lr) * DIM + h * HD + lg * 8);
    f32x4 s[8];
#pragma unroll
    for (int j = 0; j < 8; ++j) {
      f16x8 kf = *reinterpret_cast<const f16x8*>(gk + (j * 16 + lr) * DIM + h * HD + lg * 8);
      s[j] = MFMA16(afr, kf, fz);
    }

    // softmax (rows in regs; reduce over the 16 lr-lanes); bm = bias+mask f16
    const f16* bm = g_bm + ((long)(h * NW + wm) * N1 + q0) * N2;
    float* oAh = oA + (long)h * N1 * N2;
#pragma unroll
    for (int r = 0; r < 4; ++r) {
      const int row = wv * 16 + lg * 4 + r;        // tile-local q row
      const f16* bmr = bm + (long)row * N2 + lr;
#pragma unroll
      for (int j = 0; j < 8; ++j) s[j][r] += (float)bmr[16 * j];
      float m = s[0][r];
#pragma unroll
      for (int j = 1; j < 8; ++j) m = fmaxf(m, s[j][r]);
#pragma unroll
      for (int o = 8; o; o >>= 1) m = fmaxf(m, __shfl_xor(m, o));
      float sum = 0.f;
#pragma unroll
      for (int j = 0; j < 8; ++j) { s[j][r] = __expf(s[j][r] - m); sum += s[j][r]; }
#pragma unroll
      for (int o = 8; o; o >>= 1) sum += __shfl_xor(sum, o);
      const float inv = 1.0f / sum;
      float* oAr = oAh + (long)(q0 + row) * N2 + lr;
#pragma unroll
      for (int j = 0; j < 8; ++j) {
        float p = s[j][r] * inv;
        oAr[16 * j] = p;
        pS[row * 136 + 16 * j + lr] = (f16)p;
      }
    }

    // PV: X[16q x 32d] = P[16x128] * v[128x32]; pS band wave-private (in-wave
    // ds_write->ds_read ordering, no barrier).
    f32x4 x0 = fz, x1 = fz;
#pragma unroll
    for (int ks = 0; ks < 4; ++ks) {
      f16x8 pa = *reinterpret_cast<const f16x8*>(&pS[(wv * 16 + lr) * 136 + ks * 32 + lg * 8]);
      f16x8 b0 = *reinterpret_cast<const f16x8*>(&vT[lr * 136 + ks * 32 + lg * 8]);
      f16x8 b1 = *reinterpret_cast<const f16x8*>(&vT[(16 + lr) * 136 + ks * 32 + lg * 8]);
      x0 = MFMA16(pa, b0, x0);
      x1 = MFMA16(pa, b1, x1);
    }
#pragma unroll
    for (int r = 0; r < 4; ++r) {
      const int row = wv * 16 + lg * 4 + r;
      xS[row * 136 + h * HD + lr] = (f16)x0[r];
      xS[row * 136 + h * HD + 16 + lr] = (f16)x1[r];
    }
  }

  // out-proj: out[64 x 128] = xS[64 x 128] @ Wp^T + pb + residual.
  // xS bands wave-private -> no barrier needed.
  f32x4 acc[8] = {};
#pragma unroll
  for (int ks = 0; ks < 4; ++ks) {
    f16x8 a = *reinterpret_cast<const f16x8*>(&xS[(wv * 16 + lr) * 136 + ks * 32 + lg * 8]);
#pragma unroll
    for (int j = 0; j < 8; ++j) {
      f16x8 w = *reinterpret_cast<const f16x8*>(&g_wp[(j * 16 + lr) * DIM + ks * 32 + lg * 8]);
      acc[j] = MFMA16(a, w, acc[j]);
    }
  }
  const long rbase = (long)b * N1 + q0 + wv * 16 + lg * 4;
#pragma unroll
  for (int j = 0; j < 8; ++j) {
    int c = j * 16 + lr;
    float bv = pb[c];
#pragma unroll
    for (int r = 0; r < 4; ++r) {
      long idx = (rbase + r) * DIM + c;
      outX[idx] = acc[j][r] + bv + qin[idx];
    }
  }
}

extern "C" void kernel_launch(void* const* d_in, const int* in_sizes, int n_in,
                              void* d_out, int out_size, void* d_ws, size_t ws_size,
                              hipStream_t stream) {
  (void)in_sizes; (void)n_in; (void)out_size; (void)d_ws; (void)ws_size;
  const float* q    = (const float*)d_in[0];
  const float* kv   = (const float*)d_in[1];
  const float* mask = (const float*)d_in[2];
  const float* qw   = (const float*)d_in[3];
  const float* qb   = (const float*)d_in[4];
  const float* kvw  = (const float*)d_in[5];
  const float* kvb  = (const float*)d_in[6];
  const float* pw   = (const float*)d_in[7];
  const float* pb   = (const float*)d_in[8];
  const float* tbl  = (const float*)d_in[9];
  const int*   rel  = (const int*)d_in[10];

  float* outX = (float*)d_out;                     // (B, N1, DIM)
  float* outA = outX + (long)B_ * N1 * DIM;        // (B, H, N1, N2)

  hipLaunchKernelGGL(k_prep,   dim3(24640), dim3(256), 0, stream, mask, tbl, rel, qw, kvw, pw);
  hipLaunchKernelGGL(k_qproj,  dim3(1536),  dim3(256), 0, stream, q, qb);
  hipLaunchKernelGGL(k_kvproj, dim3(1024),  dim3(256), 0, stream, kv, kvb);
  hipLaunchKernelGGL(k_fused,  dim3(1536),  dim3(256), 0, stream, q, pb, outX, outA);
}